// Round 8
// baseline (363.196 us; speedup 1.0000x reference)
//
#include <hip/hip_runtime.h>

// Sequential2D: out[i] = sum_{j in [max(0,i-2), i]} X[j] @ W[i,j]^T + sum_j b[i,j]
// X (8,32768,128) f32, W (8,8,128,128) f32, b (8,8,128) f32, out (8,32768,128) f32.
//
// R9b: DRAM-burst-efficiency round (R9 resubmit; 'short4' collided with HIP's
// built-in vector type -> renamed to bf16x4). Five structures (R0,R3,R4,R5,R8)
// all pinned at 2.5-2.8 TB/s because every global access pattern was
// row-strided (16-256B chunks at 512-B stride = 25-50% burst efficiency;
// m13's 6.3 TB/s needs contiguous streams). This round every global
// load/store instruction is a 1-KB contiguous wave burst:
//   - X tile (128 rows x K=128) and W block are 64-KB SEQUENTIAL copies,
//     packed to bf16 into an XOR-swizzled LDS tile (R8-proven swizzle).
//   - epilogue: acc -> LDS f32 tile -> 64-KB SEQUENTIAL streamout (fixes
//     R8's 204-MB write amplification).
// Single 64-KB union LDS buffer, 2 barriers/j, 256 thr, 2 wg/CU co-resident.

#define NOUT  8
#define NIN   8
#define DD    128
#define BATCH 32768
#define BAND  2
#define BM    128                 // batch rows per wg (4 waves x 32 rows)

typedef __attribute__((ext_vector_type(8))) short  short8;
typedef __attribute__((ext_vector_type(4))) short  bf16x4;
typedef __attribute__((ext_vector_type(4))) float  floatx4;

__device__ __forceinline__ unsigned short f2bf(float f) {
    unsigned int u = __float_as_uint(f);
    u += 0x7fffu + ((u >> 16) & 1u);
    return (unsigned short)(u >> 16);
}

__global__ __launch_bounds__(256, 2)
void seq2d_kernel(const float* __restrict__ X,
                  const float* __restrict__ W,
                  const float* __restrict__ Bv,
                  float* __restrict__ out) {
    const int i  = blockIdx.y;
    const int m0 = blockIdx.x * BM;

    // Union buffer: [X bf16 32KB | W bf16 32KB] during compute,
    // reused as 128x128 f32 (64KB) output tile in the epilogue.
    __shared__ unsigned short sU[2 * DD * DD];
    __shared__ float sbias[DD];

    unsigned short* sX = sU;
    unsigned short* sW = sU + DD * DD;

    const int tid  = threadIdx.x;
    const int lane = tid & 63;
    const int wave = tid >> 6;          // 0..3, each owns 32 batch rows
    const int l15  = lane & 15;
    const int quad = lane >> 4;

    int jlo = i - BAND; if (jlo < 0) jlo = 0;

    if (tid < DD) {
        float s = 0.f;
        for (int j = jlo; j <= i; ++j)
            s += Bv[(i * NIN + j) * DD + tid];
        sbias[tid] = s;
    }

    // Sequential 64-KB stage: 16 x (1-KB-per-wave contiguous float4 load ->
    // bf16 pack -> swizzled ds_write_b64). fi = q*1024 + tid*4 covers the
    // 128x128 f32 matrix; row = fi>>7, col = fi&127. LDS layout: row*128
    // shorts, 16-B unit u = col>>3 stored at u ^ (row&15)  (bijective XOR,
    // conflict-free b128 fragment reads; proven in R8 on W).
    auto stage = [&](const float* __restrict__ gsrc, unsigned short* __restrict__ sdst) {
#pragma unroll
        for (int q = 0; q < 16; ++q) {
            const int fi  = q * 1024 + tid * 4;
            floatx4 v = *(const floatx4*)(gsrc + fi);
            const int row = fi >> 7;
            const int col = fi & 127;
            const int pu  = (col >> 3) ^ (row & 15);
            bf16x4 pk;
            pk[0] = (short)f2bf(v[0]); pk[1] = (short)f2bf(v[1]);
            pk[2] = (short)f2bf(v[2]); pk[3] = (short)f2bf(v[3]);
            *(bf16x4*)&sdst[row * 128 + (pu << 3) + (col & 7)] = pk;
        }
    };

    floatx4 acc[2][8];
#pragma unroll
    for (int a = 0; a < 2; ++a)
#pragma unroll
        for (int n = 0; n < 8; ++n)
            acc[a][n] = (floatx4){0.f, 0.f, 0.f, 0.f};

    for (int j = jlo; j <= i; ++j) {
        // X tile: rows m0..m0+127 of X[j] are 65536 consecutive floats.
        // W block: 65536 consecutive floats. Both stages are pure seq streams.
        stage(X + (size_t)j * (BATCH * DD) + (size_t)m0 * DD, sX);
        stage(W + (size_t)(i * NIN + j) * DD * DD, sW);
        __syncthreads();    // tiles visible

        // 4 k-steps of K=32: per wave 2 A-frags + 8 B-frags (b128, swizzled),
        // 16 MFMAs. Fragment k-unit = ks*4+quad, phys = unit ^ (row&15);
        // row&15 == l15 for both A (wave*32+mf*16+l15) and B (nf*16+l15).
#pragma unroll
        for (int ks = 0; ks < 4; ++ks) {
            const int ku = (((ks * 4 + quad) ^ l15) << 3);
            short8 a0 = *(const short8*)&sX[(wave * 32 +  0 + l15) * 128 + ku];
            short8 a1 = *(const short8*)&sX[(wave * 32 + 16 + l15) * 128 + ku];
#pragma unroll
            for (int nf = 0; nf < 8; ++nf) {
                short8 bfrag = *(const short8*)&sW[(nf * 16 + l15) * 128 + ku];
                acc[0][nf] = __builtin_amdgcn_mfma_f32_16x16x32_bf16(a0, bfrag, acc[0][nf], 0, 0, 0);
                acc[1][nf] = __builtin_amdgcn_mfma_f32_16x16x32_bf16(a1, bfrag, acc[1][nf], 0, 0, 0);
            }
        }
        __syncthreads();    // done reading before next stage overwrites
    }

    // Epilogue: acc (+bias) -> LDS f32 tile -> sequential 64-KB streamout.
    // C/D layout: row=(lane>>4)*4+r, col=lane&15 (verified R1).
    float* sO = (float*)sU;
#pragma unroll
    for (int mf = 0; mf < 2; ++mf) {
        const int r0 = wave * 32 + mf * 16 + quad * 4;
#pragma unroll
        for (int nf = 0; nf < 8; ++nf) {
            const int n_g  = nf * 16 + l15;
            const float bs = sbias[n_g];
#pragma unroll
            for (int r = 0; r < 4; ++r)
                sO[(r0 + r) * DD + n_g] = acc[mf][nf][r] + bs;
        }
    }
    __syncthreads();

    float* od = out + (size_t)i * (BATCH * DD) + (size_t)m0 * DD;
#pragma unroll
    for (int q = 0; q < 16; ++q) {
        const int fi = q * 1024 + tid * 4;
        *(floatx4*)(od + fi) = *(const floatx4*)&sO[fi];
    }
}

extern "C" void kernel_launch(void* const* d_in, const int* in_sizes, int n_in,
                              void* d_out, int out_size, void* d_ws, size_t ws_size,
                              hipStream_t stream) {
    const float* X  = (const float*)d_in[0];
    const float* W  = (const float*)d_in[1];
    const float* Bv = (const float*)d_in[2];
    float* out = (float*)d_out;

    dim3 grid(BATCH / BM, NOUT);
    seq2d_kernel<<<grid, 256, 0, stream>>>(X, W, Bv, out);
}

// Round 9
// 297.942 us; speedup vs baseline: 1.2190x; 1.2190x over previous
//
#include <hip/hip_runtime.h>

// Sequential2D: out[i] = sum_{j in [max(0,i-2), i]} X[j] @ W[i,j]^T + sum_j b[i,j]
// X (8,32768,128) f32, W (8,8,128,128) f32, b (8,8,128) f32, out (8,32768,128) f32.
//
// R10: i-fusion. R8 (deep pinned ring) and R9b (pure sequential bursts) both
// failed to move the 2.5-2.8 TB/s plateau -> neither latency nor DRAM burst
// efficiency is the limit. Remaining shared trait: logical traffic ~3x HBM
// (X read once per i = 2.6x via LLC; W re-staged per wg = 344 MB L2). This
// round each wg owns rows [m0,m0+128) and computes ALL 8 i-blocks: X is read
// exactly once by exactly one wg (no LLC re-reads, no cross-XCD sharing).
// 3-slot bf16 X ring in LDS (96 KB) for the band overlap; W (1.3 MB active
// set, L2-resident) staged per (i,j) via reg-hold: load+pack during compute,
// reg->LDS write inside the barrier window. Grid 256 = 1 wg/CU, zero tail.

#define NOUT  8
#define NIN   8
#define DD    128
#define BATCH 32768
#define BAND  2
#define BM    128

typedef __attribute__((ext_vector_type(8))) short  short8;
typedef __attribute__((ext_vector_type(4))) short  bf16x4;
typedef __attribute__((ext_vector_type(4))) float  floatx4;

__device__ __forceinline__ unsigned short f2bf(float f) {
    unsigned int u = __float_as_uint(f);
    u += 0x7fffu + ((u >> 16) & 1u);
    return (unsigned short)(u >> 16);
}

__device__ __forceinline__ bf16x4 pack4(floatx4 v) {
    bf16x4 p;
    p[0] = (short)f2bf(v[0]); p[1] = (short)f2bf(v[1]);
    p[2] = (short)f2bf(v[2]); p[3] = (short)f2bf(v[3]);
    return p;
}

__global__ __launch_bounds__(512, 2)
void seq2d_kernel(const float* __restrict__ X,
                  const float* __restrict__ W,
                  const float* __restrict__ Bv,
                  float* __restrict__ out) {
    const int m0 = blockIdx.x * BM;

    __shared__ unsigned short sX[3 * DD * DD];  // 96 KB: X ring (bf16, swizzled)
    __shared__ unsigned short sW[DD * DD];      // 32 KB: current W block

    const int tid  = threadIdx.x;
    const int lane = tid & 63;
    const int wave = tid >> 6;      // 8 waves: 4 m-blocks x 2 n-blocks
    const int wm   = wave & 3;      // rows wm*32 .. +31
    const int wn   = wave >> 2;     // cols wn*64 .. +63
    const int l15  = lane & 15;
    const int quad = lane >> 4;

    bf16x4 wh[8], xh[8];            // register holds: one 128x128 tile each

    // 128x128 f32 (64 KB contiguous) -> 8 bf16x4 hold regs per thread.
    // Per-q: 512 threads x 16 B = 1-KB-per-wave contiguous bursts.
    auto loadpack = [&](const float* __restrict__ g, bf16x4* h) {
#pragma unroll
        for (int q = 0; q < 8; ++q)
            h[q] = pack4(*(const floatx4*)(g + q * 2048 + tid * 4));
    };
    // hold regs -> swizzled LDS image: unit u = col>>3 at u ^ (row&15)
    // (R8/R9b-proven: conflict-free b128 fragment reads).
    auto writehold = [&](const bf16x4* h, unsigned short* sdst) {
#pragma unroll
        for (int q = 0; q < 8; ++q) {
            const int fi  = q * 2048 + tid * 4;
            const int row = fi >> 7;
            const int col = fi & 127;
            const int pu  = (col >> 3) ^ (row & 15);
            *(bf16x4*)&sdst[row * 128 + (pu << 3) + (col & 7)] = h[q];
        }
    };

    // Prologue: W[0,0] -> hold; X[0], X[1] -> ring slots 0,1.
    loadpack(W, wh);
    loadpack(X + (size_t)m0 * DD, xh);
    writehold(xh, sX);
    loadpack(X + (size_t)(BATCH * DD) + (size_t)m0 * DD, xh);
    writehold(xh, sX + DD * DD);

    floatx4 acc[2][4];
#pragma unroll
    for (int mf = 0; mf < 2; ++mf)
#pragma unroll
        for (int nf = 0; nf < 4; ++nf)
            acc[mf][nf] = (floatx4){0.f, 0.f, 0.f, 0.f};

    bool xpend = false;
    int  xslot = 0;

#pragma unroll 1
    for (int i = 0; i < NOUT; ++i) {
        const int jlo = (i - BAND > 0) ? (i - BAND) : 0;
#pragma unroll 1
        for (int j = jlo; j <= i; ++j) {
            __syncthreads();                     // prior step's LDS reads done
            writehold(wh, sW);                   // publish W[i,j] (reg->LDS)
            if (xpend) { writehold(xh, sX + xslot * (DD * DD)); xpend = false; }
            __syncthreads();                     // tiles visible

            // Prefetch next W pair into the hold (overlaps this step's MFMAs).
            {
                int ni = i, nj2 = j + 1;
                if (j == i) { ni = i + 1; nj2 = (i - 1 > 0) ? (i - 1) : 0; }
                if (ni < NOUT)
                    loadpack(W + (size_t)(ni * NIN + nj2) * (DD * DD), wh);
            }
            // Prefetch X[i+1] at the second j-step of the phase; its ring
            // slot ((i+1)%3, last read at step (i, i-2)) is free by the
            // write window one step later.
            if (j == jlo + 1 && i + 1 < NOUT) {
                loadpack(X + (size_t)(i + 1) * (BATCH * DD) + (size_t)m0 * DD, xh);
                xpend = true; xslot = (i + 1) % 3;
            }

            // Compute: K=128 as 4 k-steps of 32 against ring slot j%3.
            const unsigned short* sx = sX + (j % 3) * (DD * DD);
#pragma unroll
            for (int ks = 0; ks < 4; ++ks) {
                const int ku = ((ks * 4 + quad) ^ l15) << 3;
                short8 a[2], b[4];
#pragma unroll
                for (int mf = 0; mf < 2; ++mf)
                    a[mf] = *(const short8*)&sx[(wm * 32 + mf * 16 + l15) * 128 + ku];
#pragma unroll
                for (int nf = 0; nf < 4; ++nf)
                    b[nf] = *(const short8*)&sW[(wn * 64 + nf * 16 + l15) * 128 + ku];
#pragma unroll
                for (int mf = 0; mf < 2; ++mf)
#pragma unroll
                    for (int nf = 0; nf < 4; ++nf)
                        acc[mf][nf] = __builtin_amdgcn_mfma_f32_16x16x32_bf16(
                            a[mf], b[nf], acc[mf][nf], 0, 0, 0);
            }

            if (j == i) {
                // Epilogue for block-row i. C/D layout row=(lane>>4)*4+r,
                // col=lane&15 (verified R1). Bias read direct (4-KB hot region).
                float* outi = out + (size_t)i * (BATCH * DD);
#pragma unroll
                for (int nf = 0; nf < 4; ++nf) {
                    const int n_g = wn * 64 + nf * 16 + l15;
                    float bs = 0.f;
                    for (int jj = jlo; jj <= i; ++jj)
                        bs += Bv[(i * NIN + jj) * DD + n_g];
#pragma unroll
                    for (int mf = 0; mf < 2; ++mf) {
                        const int m_b = m0 + wm * 32 + mf * 16 + quad * 4;
#pragma unroll
                        for (int r = 0; r < 4; ++r)
                            outi[(size_t)(m_b + r) * DD + n_g] = acc[mf][nf][r] + bs;
                        acc[mf][nf] = (floatx4){0.f, 0.f, 0.f, 0.f};
                    }
                }
            }
        }
    }
}

extern "C" void kernel_launch(void* const* d_in, const int* in_sizes, int n_in,
                              void* d_out, int out_size, void* d_ws, size_t ws_size,
                              hipStream_t stream) {
    const float* X  = (const float*)d_in[0];
    const float* W  = (const float*)d_in[1];
    const float* Bv = (const float*)d_in[2];
    float* out = (float*)d_out;

    dim3 grid(BATCH / BM);
    seq2d_kernel<<<grid, 512, 0, stream>>>(X, W, Bv, out);
}